// Round 14
// baseline (285.749 us; speedup 1.0000x reference)
//
#include <hip/hip_runtime.h>
#include <hip/hip_fp16.h>

#define N_NODES 50000
#define N_EDGES 800000

typedef _Float16 half8 __attribute__((ext_vector_type(8)));
typedef float floatx4 __attribute__((ext_vector_type(4)));

// ---------------------------------------------------------------------------
// setup: y=0 rowptr (lower_bound over sorted src); y=1 cast lw0 -> fp16;
//        y=2/3 fold lw1/lw2 (64x256) to planar K=192 fp16 matching agg layout
//        [i, ch*64+f], ch in {0:mean(heads0+1), 1:a2, 2:a3}.
// ---------------------------------------------------------------------------
__global__ __launch_bounds__(256) void setup_kernel(const int* __restrict__ src,
                                                    int* __restrict__ row_ptr,
                                                    const float* __restrict__ lw0,
                                                    const float* __restrict__ lw1,
                                                    const float* __restrict__ lw2,
                                                    _Float16* __restrict__ w0p,
                                                    _Float16* __restrict__ w1p,
                                                    _Float16* __restrict__ w2p) {
    int idx = blockIdx.x * 256 + threadIdx.x;
    if (blockIdx.y == 0) {
        if (idx > N_NODES) return;
        int lo = 0, hi = N_EDGES;
        while (lo < hi) {
            int mid = (lo + hi) >> 1;
            if (src[mid] < idx) lo = mid + 1; else hi = mid;
        }
        row_ptr[idx] = lo;
        return;
    }
    if (blockIdx.y == 1) {
        if (idx < 64 * 128) w0p[idx] = (_Float16)lw0[idx];
        return;
    }
    if (idx >= 64 * 192) return;
    int o = idx / 192, r = idx % 192;
    int ch = r >> 6, f = r & 63;
    const float* lw = (blockIdx.y == 2) ? lw1 : lw2;
    float v;
    if (ch == 0)      v = lw[o * 256 + f * 4 + 0] + lw[o * 256 + f * 4 + 1];
    else if (ch == 1) v = lw[o * 256 + f * 4 + 2];
    else              v = lw[o * 256 + f * 4 + 3];
    (blockIdx.y == 2 ? w1p : w2p)[idx] = (_Float16)v;
}

// ---------------------------------------------------------------------------
// lin via MFMA 16x16x32 f16 (layout verified R8). 4 waves, 16 rows x 64 cols
// per wave, fragments direct from global. TIn=float folds the x cast in.
// Score epilogue stores E = exp(score) (deferred-normalization softmax).
// ---------------------------------------------------------------------------
template <typename TIn, int K>
__global__ __launch_bounds__(256) void lin_kernel(const TIn* __restrict__ in,
                                                  const _Float16* __restrict__ w,
                                                  const float* __restrict__ b,
                                                  const float* __restrict__ aw,
                                                  _Float16* __restrict__ h,
                                                  float2* __restrict__ s, int n) {
    const int t = threadIdx.x;
    const int l = t & 63;
    const int wv = t >> 6;
    const int arow = l & 15;
    const int kg = l >> 4;
    const long rowbase = (long)blockIdx.x * 64 + wv * 16;
    long arow_g = rowbase + arow;
    if (arow_g >= n) arow_g = n - 1;

    floatx4 acc[4] = {};

    for (int kc = 0; kc < K; kc += 32) {
        const int ks = kc + kg * 8;
        half8 a;
        if (sizeof(TIn) == 4) {
            const TIn* ap = in + arow_g * K + ks;
            #pragma unroll
            for (int j = 0; j < 8; ++j) a[j] = (_Float16)ap[j];
        } else {
            a = *(const half8*)((const _Float16*)in + arow_g * K + ks);
        }
        #pragma unroll
        for (int ct = 0; ct < 4; ++ct) {
            half8 bb = *(const half8*)(w + (long)(ct * 16 + arow) * K + ks);
            acc[ct] = __builtin_amdgcn_mfma_f32_16x16x32_f16(a, bb, acc[ct], 0, 0, 0);
        }
    }

    const int c = l & 15;
    const int rq = l >> 4;
    float bias[4], a2c[4], a3c[4];
    #pragma unroll
    for (int ct = 0; ct < 4; ++ct) {
        int col = ct * 16 + c;
        bias[ct] = b[col];
        a2c[ct] = aw[2 * 128 + col] + aw[2 * 128 + 64 + col];
        a3c[ct] = aw[3 * 128 + col] + aw[3 * 128 + 64 + col];
    }
    #pragma unroll
    for (int r = 0; r < 4; ++r) {
        long row = rowbase + rq * 4 + r;
        bool ok = row < n;
        float q2 = 0.f, q3 = 0.f;
        _Float16 hv[4];
        #pragma unroll
        for (int ct = 0; ct < 4; ++ct) {
            float u = acc[ct][r] + bias[ct];
            u = u > 0.f ? u : 0.2f * u;
            q2 += u * a2c[ct];
            q3 += u * a3c[ct];
            hv[ct] = (_Float16)u;
        }
        if (ok) {
            #pragma unroll
            for (int ct = 0; ct < 4; ++ct) h[row * 64 + ct * 16 + c] = hv[ct];
        }
        #pragma unroll
        for (int o = 1; o < 16; o <<= 1) {
            q2 += __shfl_xor(q2, o);
            q3 += __shfl_xor(q3, o);
        }
        if (c == 0 && ok) s[row] = make_float2(__expf(q2), __expf(q3));
    }
}

// ---------------------------------------------------------------------------
// Single-pass aggregation, deferred softmax normalization, EIGHTH-WAVE edge
// parallelism. Wave per node (4/block, grid 12500, no LDS).
// Lane: e8 = l>>3 (edge slot 0..7), fo = l&7 (feature octet -> features
// fo*8..fo*8+7 via one f16x8 16B load; 8 lanes cover the 128B row).
// One VMEM instruction covers 8 edges (16B/lane = coalescing sweet spot).
// Per 16-edge step: 2 h-loads + 2 E-loads in flight. Edge-id distribution
// via __shfl (per-lane index legal). Eighths partition edges ->
// xor-8/16/32 merge yields true segment sums on every lane.
// ---------------------------------------------------------------------------
__global__ __launch_bounds__(256) void agg_kernel(const _Float16* __restrict__ hfeat,
                                                  const float2* __restrict__ E,
                                                  const int* __restrict__ dst,
                                                  const int* __restrict__ row_ptr,
                                                  _Float16* __restrict__ out_h,
                                                  float* __restrict__ out_f,
                                                  int final_layer, int n) {
    const int t = threadIdx.x;
    const int l = t & 63;
    const int i = blockIdx.x * 4 + (t >> 6);
    if (i >= n) return;
    const int r0 = row_ptr[i], r1 = row_ptr[i + 1];
    const int deg = r1 - r0;
    const int e8 = l >> 3;     // edge slot 0..7
    const int fo = l & 7;      // feature octet

    if (deg == 0) {
        if (!final_layer) {
            out_h[(long)i * 192 + l] = (_Float16)0.f;
            out_h[(long)i * 192 + 64 + l] = (_Float16)0.f;
            out_h[(long)i * 192 + 128 + l] = (_Float16)0.f;
        } else {
            out_f[(long)i * 64 + l] = 0.f;
        }
        return;
    }

    float am[8] = {}, a2[8] = {}, a3[8] = {};
    float S2 = 0.f, S3 = 0.f;

    for (int c0 = r0; c0 < r1; c0 += 64) {
        const int cn = min(64, r1 - c0);
        const int dl = dst[c0 + min(l, cn - 1)];   // coalesced edge-id load

        for (int jj = 0; jj < cn; jj += 16) {
            // two 8-edge groups; this lane handles edge jj + g*8 + e8
            int dg[2]; float vg[2];
            #pragma unroll
            for (int g = 0; g < 2; ++g) {
                int e = jj + g * 8 + e8;
                int ec = e < cn ? e : cn - 1;
                dg[g] = __shfl(dl, ec);            // ds_bpermute: per-lane idx OK
                vg[g] = e < cn ? 1.f : 0.f;
            }
            half8 hv[2]; float2 Ev[2];
            #pragma unroll
            for (int g = 0; g < 2; ++g) {
                hv[g] = *(const half8*)(hfeat + (long)dg[g] * 64 + fo * 8);
                Ev[g] = E[dg[g]];
            }
            #pragma unroll
            for (int g = 0; g < 2; ++g) {
                float vm = vg[g];
                float e2 = vm * Ev[g].x, e3 = vm * Ev[g].y;
                S2 += e2; S3 += e3;
                #pragma unroll
                for (int k = 0; k < 8; ++k) {
                    float hf = (float)hv[g][k];
                    am[k] += vm * hf;
                    a2[k] += e2 * hf;
                    a3[k] += e3 * hf;
                }
            }
        }
    }

    // merge eighths: lanes {fo, fo+8, ..., fo+56} all get the segment sums
    #pragma unroll
    for (int o = 8; o < 64; o <<= 1) {
        #pragma unroll
        for (int k = 0; k < 8; ++k) {
            am[k] += __shfl_xor(am[k], o);
            a2[k] += __shfl_xor(a2[k], o);
            a3[k] += __shfl_xor(a3[k], o);
        }
        S2 += __shfl_xor(S2, o);
        S3 += __shfl_xor(S3, o);
    }

    const float inv_deg = 1.f / (float)deg;
    const float i2 = 1.f / S2, i3 = 1.f / S3;

    if (e8 == 0) {
        if (!final_layer) {
            half8 o0, o1, o2;
            #pragma unroll
            for (int k = 0; k < 8; ++k) {
                o0[k] = (_Float16)fmaxf(am[k] * inv_deg, 0.f);
                o1[k] = (_Float16)fmaxf(a2[k] * i2, 0.f);
                o2[k] = (_Float16)fmaxf(a3[k] * i3, 0.f);
            }
            *(half8*)(out_h + (long)i * 192 + fo * 8)       = o0;
            *(half8*)(out_h + (long)i * 192 + 64 + fo * 8)  = o1;
            *(half8*)(out_h + (long)i * 192 + 128 + fo * 8) = o2;
        } else {
            floatx4 oa, ob;
            #pragma unroll
            for (int k = 0; k < 4; ++k) {
                oa[k] = fmaxf(0.5f * inv_deg * am[k] + 0.25f * (a2[k] * i2 + a3[k] * i3), 0.f);
                ob[k] = fmaxf(0.5f * inv_deg * am[k + 4] + 0.25f * (a2[k + 4] * i2 + a3[k + 4] * i3), 0.f);
            }
            *(floatx4*)(out_f + (long)i * 64 + fo * 8)     = oa;
            *(floatx4*)(out_f + (long)i * 64 + fo * 8 + 4) = ob;
        }
    }
}

// ---------------------------------------------------------------------------
extern "C" void kernel_launch(void* const* d_in, const int* in_sizes, int n_in,
                              void* d_out, int out_size, void* d_ws, size_t ws_size,
                              hipStream_t stream) {
    const float* x = (const float*)d_in[0];
    const float* lw[3] = {(const float*)d_in[1], (const float*)d_in[5], (const float*)d_in[9]};
    const float* lb[3] = {(const float*)d_in[2], (const float*)d_in[6], (const float*)d_in[10]};
    const float* aw[3] = {(const float*)d_in[3], (const float*)d_in[7], (const float*)d_in[11]};
    const int* src = (const int*)d_in[13];
    const int* dst = (const int*)d_in[14];
    float* out = (float*)d_out;

    const int N = N_NODES;

    // ws layout: hA,hB: N*64 f16 | g: N*192 f16 | sA,sB: N float2
    //            | w0p 64*128 f16 | w1p,w2p 64*192 f16 | row_ptr N+1 int
    _Float16* hA = (_Float16*)d_ws;
    _Float16* hB = hA + (size_t)N * 64;
    _Float16* g  = hB + (size_t)N * 64;
    float2* sA = (float2*)(g + (size_t)N * 192);
    float2* sB = sA + N;
    _Float16* w0p = (_Float16*)(sB + N);
    _Float16* w1p = w0p + 64 * 128;
    _Float16* w2p = w1p + 64 * 192;
    int* row_ptr = (int*)(w2p + 64 * 192);

    const int lin_grid = (N + 63) / 64;      // 782
    const int node_grid = (N + 3) / 4;       // 12500

    setup_kernel<<<dim3(196, 4), 256, 0, stream>>>(src, row_ptr, lw[0], lw[1], lw[2],
                                                   w0p, w1p, w2p);

    // layer 0: x (fp32, cast inline) -> hA, sA(=E)
    lin_kernel<float, 128><<<lin_grid, 256, 0, stream>>>(x, w0p, lb[0], aw[0], hA, sA, N);

    // layer 0 agg -> g ; layer 1 lin: g -> hB, sB
    agg_kernel<<<node_grid, 256, 0, stream>>>(hA, sA, dst, row_ptr, g, out, 0, N);
    lin_kernel<_Float16, 192><<<lin_grid, 256, 0, stream>>>(g, w1p, lb[1], aw[1], hB, sB, N);

    // layer 1 agg -> g ; layer 2 lin: g -> hA, sA
    agg_kernel<<<node_grid, 256, 0, stream>>>(hB, sB, dst, row_ptr, g, out, 0, N);
    lin_kernel<_Float16, 192><<<lin_grid, 256, 0, stream>>>(g, w2p, lb[2], aw[2], hA, sA, N);

    // layer 2 final aggregation -> out (fp32)
    agg_kernel<<<node_grid, 256, 0, stream>>>(hA, sA, dst, row_ptr, g, out, 1, N);
}

// Round 15
// 242.515 us; speedup vs baseline: 1.1783x; 1.1783x over previous
//
#include <hip/hip_runtime.h>
#include <hip/hip_fp16.h>

#define N_NODES 50000
#define N_EDGES 800000

typedef _Float16 half8 __attribute__((ext_vector_type(8)));
typedef _Float16 f16x4 __attribute__((ext_vector_type(4)));
typedef float floatx4 __attribute__((ext_vector_type(4)));

// ---------------------------------------------------------------------------
// setup: y=0 rowptr (lower_bound over sorted src); y=1 cast lw0 -> fp16;
//        y=2/3 fold lw1/lw2 (64x256) to planar K=192 fp16 matching agg layout
//        [i, ch*64+f], ch in {0:mean(heads0+1), 1:a2, 2:a3}.
// ---------------------------------------------------------------------------
__global__ __launch_bounds__(256) void setup_kernel(const int* __restrict__ src,
                                                    int* __restrict__ row_ptr,
                                                    const float* __restrict__ lw0,
                                                    const float* __restrict__ lw1,
                                                    const float* __restrict__ lw2,
                                                    _Float16* __restrict__ w0p,
                                                    _Float16* __restrict__ w1p,
                                                    _Float16* __restrict__ w2p) {
    int idx = blockIdx.x * 256 + threadIdx.x;
    if (blockIdx.y == 0) {
        if (idx > N_NODES) return;
        int lo = 0, hi = N_EDGES;
        while (lo < hi) {
            int mid = (lo + hi) >> 1;
            if (src[mid] < idx) lo = mid + 1; else hi = mid;
        }
        row_ptr[idx] = lo;
        return;
    }
    if (blockIdx.y == 1) {
        if (idx < 64 * 128) w0p[idx] = (_Float16)lw0[idx];
        return;
    }
    if (idx >= 64 * 192) return;
    int o = idx / 192, r = idx % 192;
    int ch = r >> 6, f = r & 63;
    const float* lw = (blockIdx.y == 2) ? lw1 : lw2;
    float v;
    if (ch == 0)      v = lw[o * 256 + f * 4 + 0] + lw[o * 256 + f * 4 + 1];
    else if (ch == 1) v = lw[o * 256 + f * 4 + 2];
    else              v = lw[o * 256 + f * 4 + 3];
    (blockIdx.y == 2 ? w1p : w2p)[idx] = (_Float16)v;
}

// ---------------------------------------------------------------------------
// lin via MFMA 16x16x32 f16 (layout verified R8). 4 waves, 16 rows x 64 cols
// per wave, fragments direct from global. TIn=float folds the x cast in.
// Score epilogue stores E = exp(score) (deferred-normalization softmax).
// ---------------------------------------------------------------------------
template <typename TIn, int K>
__global__ __launch_bounds__(256) void lin_kernel(const TIn* __restrict__ in,
                                                  const _Float16* __restrict__ w,
                                                  const float* __restrict__ b,
                                                  const float* __restrict__ aw,
                                                  _Float16* __restrict__ h,
                                                  float2* __restrict__ s, int n) {
    const int t = threadIdx.x;
    const int l = t & 63;
    const int wv = t >> 6;
    const int arow = l & 15;
    const int kg = l >> 4;
    const long rowbase = (long)blockIdx.x * 64 + wv * 16;
    long arow_g = rowbase + arow;
    if (arow_g >= n) arow_g = n - 1;

    floatx4 acc[4] = {};

    for (int kc = 0; kc < K; kc += 32) {
        const int ks = kc + kg * 8;
        half8 a;
        if (sizeof(TIn) == 4) {
            const TIn* ap = in + arow_g * K + ks;
            #pragma unroll
            for (int j = 0; j < 8; ++j) a[j] = (_Float16)ap[j];
        } else {
            a = *(const half8*)((const _Float16*)in + arow_g * K + ks);
        }
        #pragma unroll
        for (int ct = 0; ct < 4; ++ct) {
            half8 bb = *(const half8*)(w + (long)(ct * 16 + arow) * K + ks);
            acc[ct] = __builtin_amdgcn_mfma_f32_16x16x32_f16(a, bb, acc[ct], 0, 0, 0);
        }
    }

    const int c = l & 15;
    const int rq = l >> 4;
    float bias[4], a2c[4], a3c[4];
    #pragma unroll
    for (int ct = 0; ct < 4; ++ct) {
        int col = ct * 16 + c;
        bias[ct] = b[col];
        a2c[ct] = aw[2 * 128 + col] + aw[2 * 128 + 64 + col];
        a3c[ct] = aw[3 * 128 + col] + aw[3 * 128 + 64 + col];
    }
    #pragma unroll
    for (int r = 0; r < 4; ++r) {
        long row = rowbase + rq * 4 + r;
        bool ok = row < n;
        float q2 = 0.f, q3 = 0.f;
        _Float16 hv[4];
        #pragma unroll
        for (int ct = 0; ct < 4; ++ct) {
            float u = acc[ct][r] + bias[ct];
            u = u > 0.f ? u : 0.2f * u;
            q2 += u * a2c[ct];
            q3 += u * a3c[ct];
            hv[ct] = (_Float16)u;
        }
        if (ok) {
            #pragma unroll
            for (int ct = 0; ct < 4; ++ct) h[row * 64 + ct * 16 + c] = hv[ct];
        }
        #pragma unroll
        for (int o = 1; o < 16; o <<= 1) {
            q2 += __shfl_xor(q2, o);
            q3 += __shfl_xor(q3, o);
        }
        if (c == 0 && ok) s[row] = make_float2(__expf(q2), __expf(q3));
    }
}

// ---------------------------------------------------------------------------
// Single-pass aggregation, deferred softmax normalization, quarter-wave edge
// parallelism (R13 mapping — best measured; eighth-wave regressed: merge tree
// & mask overhead grow with per-lane accumulators).
// Lane: q = l>>4 (edge slot 0..3), fl = l&15 (feature quad, f16x4 8B load;
// 16 lanes cover the 128B row). Main loop: UNMASKED 16-edge steps (4 groups,
// 8 gathers in flight, zero mask VALU). Tail: masked 8-edge steps (R13).
// Quarters partition edges -> xor-16/32 merge gives true segment sums.
// ---------------------------------------------------------------------------
__global__ __launch_bounds__(256) void agg_kernel(const _Float16* __restrict__ hfeat,
                                                  const float2* __restrict__ E,
                                                  const int* __restrict__ dst,
                                                  const int* __restrict__ row_ptr,
                                                  _Float16* __restrict__ out_h,
                                                  float* __restrict__ out_f,
                                                  int final_layer, int n) {
    const int t = threadIdx.x;
    const int l = t & 63;
    const int i = blockIdx.x * 4 + (t >> 6);
    if (i >= n) return;
    const int r0 = row_ptr[i], r1 = row_ptr[i + 1];
    const int deg = r1 - r0;
    const int q = l >> 4;      // edge slot 0..3
    const int fl = l & 15;     // feature quad

    if (deg == 0) {
        if (!final_layer) {
            if (q < 3) *(f16x4*)(out_h + (long)i * 192 + q * 64 + fl * 4) =
                f16x4{(_Float16)0.f, (_Float16)0.f, (_Float16)0.f, (_Float16)0.f};
        } else if (q == 0) {
            *(floatx4*)(out_f + (long)i * 64 + fl * 4) = floatx4{0.f, 0.f, 0.f, 0.f};
        }
        return;
    }

    float am[4] = {}, a2[4] = {}, a3[4] = {};
    float S2 = 0.f, S3 = 0.f;

    for (int c0 = r0; c0 < r1; c0 += 64) {
        const int cn = min(64, r1 - c0);
        const int dl = dst[c0 + min(l, cn - 1)];   // coalesced edge-id load

        int jj = 0;
        // ---- unmasked main: 16 edges/step, 4 groups, 8 gathers in flight ----
        for (; jj + 16 <= cn; jj += 16) {
            int dg[4];
            #pragma unroll
            for (int g = 0; g < 4; ++g)
                dg[g] = __shfl(dl, jj + g * 4 + q);   // index < cn guaranteed
            f16x4 hv[4]; float2 Ev[4];
            #pragma unroll
            for (int g = 0; g < 4; ++g) {
                hv[g] = *(const f16x4*)(hfeat + (long)dg[g] * 64 + fl * 4);
                Ev[g] = E[dg[g]];
            }
            #pragma unroll
            for (int g = 0; g < 4; ++g) {
                float e2 = Ev[g].x, e3 = Ev[g].y;
                S2 += e2; S3 += e3;
                #pragma unroll
                for (int k = 0; k < 4; ++k) {
                    float hf = (float)hv[g][k];
                    am[k] += hf;
                    a2[k] += e2 * hf;
                    a3[k] += e3 * hf;
                }
            }
        }
        // ---- masked tail: 8 edges/step (R13 path) ----
        for (; jj < cn; jj += 8) {
            int dg[2]; float vg[2];
            #pragma unroll
            for (int g = 0; g < 2; ++g) {
                int e = jj + g * 4 + q;
                int ec = e < cn ? e : cn - 1;
                dg[g] = __shfl(dl, ec);
                vg[g] = e < cn ? 1.f : 0.f;
            }
            f16x4 hv[2]; float2 Ev[2];
            #pragma unroll
            for (int g = 0; g < 2; ++g) {
                hv[g] = *(const f16x4*)(hfeat + (long)dg[g] * 64 + fl * 4);
                Ev[g] = E[dg[g]];
            }
            #pragma unroll
            for (int g = 0; g < 2; ++g) {
                float vm = vg[g];
                float e2 = vm * Ev[g].x, e3 = vm * Ev[g].y;
                S2 += e2; S3 += e3;
                #pragma unroll
                for (int k = 0; k < 4; ++k) {
                    float hf = (float)hv[g][k];
                    am[k] += vm * hf;
                    a2[k] += e2 * hf;
                    a3[k] += e3 * hf;
                }
            }
        }
    }

    // merge quarters: lanes {fl, fl+16, fl+32, fl+48} all get the segment sums
    #pragma unroll
    for (int o = 16; o < 64; o <<= 1) {
        #pragma unroll
        for (int k = 0; k < 4; ++k) {
            am[k] += __shfl_xor(am[k], o);
            a2[k] += __shfl_xor(a2[k], o);
            a3[k] += __shfl_xor(a3[k], o);
        }
        S2 += __shfl_xor(S2, o);
        S3 += __shfl_xor(S3, o);
    }

    const float inv_deg = 1.f / (float)deg;
    const float i2 = 1.f / S2, i3 = 1.f / S3;

    if (!final_layer) {
        if (q == 0) {
            f16x4 o0, o1, o2;
            #pragma unroll
            for (int k = 0; k < 4; ++k) {
                o0[k] = (_Float16)fmaxf(am[k] * inv_deg, 0.f);
                o1[k] = (_Float16)fmaxf(a2[k] * i2, 0.f);
                o2[k] = (_Float16)fmaxf(a3[k] * i3, 0.f);
            }
            *(f16x4*)(out_h + (long)i * 192 + fl * 4)       = o0;
            *(f16x4*)(out_h + (long)i * 192 + 64 + fl * 4)  = o1;
            *(f16x4*)(out_h + (long)i * 192 + 128 + fl * 4) = o2;
        }
    } else {
        if (q == 0) {
            floatx4 o;
            #pragma unroll
            for (int k = 0; k < 4; ++k)
                o[k] = fmaxf(0.5f * inv_deg * am[k] + 0.25f * (a2[k] * i2 + a3[k] * i3), 0.f);
            *(floatx4*)(out_f + (long)i * 64 + fl * 4) = o;
        }
    }
}

// ---------------------------------------------------------------------------
extern "C" void kernel_launch(void* const* d_in, const int* in_sizes, int n_in,
                              void* d_out, int out_size, void* d_ws, size_t ws_size,
                              hipStream_t stream) {
    const float* x = (const float*)d_in[0];
    const float* lw[3] = {(const float*)d_in[1], (const float*)d_in[5], (const float*)d_in[9]};
    const float* lb[3] = {(const float*)d_in[2], (const float*)d_in[6], (const float*)d_in[10]};
    const float* aw[3] = {(const float*)d_in[3], (const float*)d_in[7], (const float*)d_in[11]};
    const int* src = (const int*)d_in[13];
    const int* dst = (const int*)d_in[14];
    float* out = (float*)d_out;

    const int N = N_NODES;

    // ws layout: hA,hB: N*64 f16 | g: N*192 f16 | sA,sB: N float2
    //            | w0p 64*128 f16 | w1p,w2p 64*192 f16 | row_ptr N+1 int
    _Float16* hA = (_Float16*)d_ws;
    _Float16* hB = hA + (size_t)N * 64;
    _Float16* g  = hB + (size_t)N * 64;
    float2* sA = (float2*)(g + (size_t)N * 192);
    float2* sB = sA + N;
    _Float16* w0p = (_Float16*)(sB + N);
    _Float16* w1p = w0p + 64 * 128;
    _Float16* w2p = w1p + 64 * 192;
    int* row_ptr = (int*)(w2p + 64 * 192);

    const int lin_grid = (N + 63) / 64;      // 782
    const int node_grid = (N + 3) / 4;       // 12500

    setup_kernel<<<dim3(196, 4), 256, 0, stream>>>(src, row_ptr, lw[0], lw[1], lw[2],
                                                   w0p, w1p, w2p);

    // layer 0: x (fp32, cast inline) -> hA, sA(=E)
    lin_kernel<float, 128><<<lin_grid, 256, 0, stream>>>(x, w0p, lb[0], aw[0], hA, sA, N);

    // layer 0 agg -> g ; layer 1 lin: g -> hB, sB
    agg_kernel<<<node_grid, 256, 0, stream>>>(hA, sA, dst, row_ptr, g, out, 0, N);
    lin_kernel<_Float16, 192><<<lin_grid, 256, 0, stream>>>(g, w1p, lb[1], aw[1], hB, sB, N);

    // layer 1 agg -> g ; layer 2 lin: g -> hA, sA
    agg_kernel<<<node_grid, 256, 0, stream>>>(hB, sB, dst, row_ptr, g, out, 0, N);
    lin_kernel<_Float16, 192><<<lin_grid, 256, 0, stream>>>(g, w2p, lb[2], aw[2], hA, sA, N);

    // layer 2 final aggregation -> out (fp32)
    agg_kernel<<<node_grid, 256, 0, stream>>>(hA, sA, dst, row_ptr, g, out, 1, N);
}